// Round 1
// baseline (117.157 us; speedup 1.0000x reference)
//
#include <hip/hip_runtime.h>
#include <hip/hip_bf16.h>

#define NN   8192
#define INF_ 256
#define OUTF 128
#define SLOPE 0.2f

typedef float f32x4  __attribute__((ext_vector_type(4)));
typedef float f32x16 __attribute__((ext_vector_type(16)));
typedef short bf16x8 __attribute__((ext_vector_type(8)));
typedef int   i32x4  __attribute__((ext_vector_type(4)));
typedef unsigned short u16;
typedef u16 u16x4 __attribute__((ext_vector_type(4)));

__device__ __forceinline__ u16 f2bf(float f) {
  return __builtin_bit_cast(u16, __float2bfloat16(f));
}

// ---------------------------------------------------------------------------
// K1: h = X @ W (fp32). Writes:
//  - hbF: bf16 copy of h in MFMA-B-fragment order:
//      elem(j,col) -> ((J*4 + c)*64 + x + 32*g)*8 + e
//      J=j>>4, g=(j>>3)&1, e=j&7, c=col>>5, x=col&31
//  - s1[i] = h[i,:]@a1, s2[i] = h[i,:]@a2  (fp32)
// 256 blocks x 256 threads; block = 32 rows. Thread = 4 rows x 4 cols.
// ---------------------------------------------------------------------------
__global__ __launch_bounds__(256) void gat_k1(
    const float* __restrict__ X, const float* __restrict__ W,
    const float* __restrict__ a, u16* __restrict__ hbF,
    float* __restrict__ s1, float* __restrict__ s2) {
  __shared__ float xs[32 * INF_];
  const int t = threadIdx.x;
  const int r0 = blockIdx.x * 32;
  {
    const f32x4* src = (const f32x4*)(X + (size_t)r0 * INF_);
    f32x4* dst = (f32x4*)xs;
    for (int i = t; i < 32 * INF_ / 4; i += 256) dst[i] = src[i];
  }
  __syncthreads();
  const int cg = t & 31;   // 4-col group
  const int rg = t >> 5;   // 4-row group (0..7)
  float acc[4][4];
#pragma unroll
  for (int i = 0; i < 4; i++)
#pragma unroll
    for (int j = 0; j < 4; j++) acc[i][j] = 0.f;

  for (int k = 0; k < INF_; k += 4) {
    f32x4 xv[4];
#pragma unroll
    for (int i = 0; i < 4; i++) xv[i] = *(const f32x4*)&xs[(rg * 4 + i) * INF_ + k];
#pragma unroll
    for (int kk = 0; kk < 4; kk++) {
      f32x4 wv = *(const f32x4*)&W[(k + kk) * OUTF + cg * 4];
#pragma unroll
      for (int i = 0; i < 4; i++)
#pragma unroll
        for (int j = 0; j < 4; j++) acc[i][j] = fmaf(xv[i][kk], wv[j], acc[i][j]);
    }
  }

  // s1/s2: dot each row with a1/a2, reduce over the 32 col-group lanes
  f32x4 a1v = *(const f32x4*)&a[cg * 4];
  f32x4 a2v = *(const f32x4*)&a[OUTF + cg * 4];
  float p1[4], p2[4];
#pragma unroll
  for (int i = 0; i < 4; i++) {
    p1[i] = acc[i][0] * a1v[0] + acc[i][1] * a1v[1] + acc[i][2] * a1v[2] + acc[i][3] * a1v[3];
    p2[i] = acc[i][0] * a2v[0] + acc[i][1] * a2v[1] + acc[i][2] * a2v[2] + acc[i][3] * a2v[3];
  }
#pragma unroll
  for (int m = 1; m < 32; m <<= 1) {
#pragma unroll
    for (int i = 0; i < 4; i++) {
      p1[i] += __shfl_xor(p1[i], m);
      p2[i] += __shfl_xor(p2[i], m);
    }
  }
  if (cg == 0) {
#pragma unroll
    for (int i = 0; i < 4; i++) {
      s1[r0 + rg * 4 + i] = p1[i];
      s2[r0 + rg * 4 + i] = p2[i];
    }
  }

  // hbF scatter: per col, 4 consecutive-e bf16 -> one 8B store
  const int R0 = r0 + rg * 4;
  const int J  = R0 >> 4;
  const int gg = (R0 >> 3) & 1;
  const int e0 = R0 & 7;
#pragma unroll
  for (int j = 0; j < 4; j++) {
    const int C = cg * 4 + j;
    u16x4 pk;
#pragma unroll
    for (int i = 0; i < 4; i++) pk[i] = f2bf(acc[i][j]);
    size_t flat = ((size_t)(J * 4 + (C >> 5)) * 64 + (C & 31) + 32 * gg) * 8 + e0;
    *(u16x4*)(hbF + flat) = pk;
  }
}

// ---------------------------------------------------------------------------
// K2: s2max = max(s2)
// ---------------------------------------------------------------------------
__global__ __launch_bounds__(256) void gat_k2(const float* __restrict__ s2,
                                              float* __restrict__ s2m) {
  __shared__ float sm[4];
  const int t = threadIdx.x;
  float m = -1e30f;
  for (int i = t; i < NN; i += 256) m = fmaxf(m, s2[i]);
#pragma unroll
  for (int k = 1; k < 64; k <<= 1) m = fmaxf(m, __shfl_xor(m, k));
  if ((t & 63) == 0) sm[t >> 6] = m;
  __syncthreads();
  if (t == 0) *s2m = fmaxf(fmaxf(sm[0], sm[1]), fmaxf(sm[2], sm[3]));
}

// ---------------------------------------------------------------------------
// K3: fused mask+lrelu+softmax+PV. 256 blocks x 8 waves.
// Block = 32 output rows; waves j-split (wave w does chunks w, w+8, ...).
// Chunk = 16 j. A-frag: P[row=l&31][k=8*(l>>5)+e]; B from hbF (frag order).
// ---------------------------------------------------------------------------
__device__ __forceinline__ void st16(float* dst, const f32x16& A, int g) {
#pragma unroll
  for (int r = 0; r < 16; r++) {
    const int dr = (r & 3) + 8 * (r >> 2) + 4 * g;
    dst[dr * 128] = A[r];
  }
}
__device__ __forceinline__ void ad16(float* dst, const f32x16& A, int g) {
#pragma unroll
  for (int r = 0; r < 16; r++) {
    const int dr = (r & 3) + 8 * (r >> 2) + 4 * g;
    dst[dr * 128] += A[r];
  }
}

__global__ __launch_bounds__(512, 2) void gat_k3(
    const int* __restrict__ adj, const u16* __restrict__ hbF,
    const float* __restrict__ s1g, const float* __restrict__ s2g,
    const float* __restrict__ s2maxp, float* __restrict__ out) {
  __shared__ float lred[4 * 32 * 128];  // 64 KB, phase-multiplexed
  const int t = threadIdx.x;
  const int w = t >> 6;
  const int l = t & 63;
  const int r0 = blockIdx.x * 32;
  const int row = l & 31;
  const int g = l >> 5;

  const float s1r = s1g[r0 + row];
  const float s2m = *s2maxp;
  float Mi = s1r + s2m;
  Mi = fmaxf(Mi, SLOPE * Mi);  // lrelu of upper bound >= all row scores

  f32x16 acc0 = 0.f, acc1 = 0.f, acc2 = 0.f, acc3 = 0.f;

  const i32x4* adjp = (const i32x4*)(adj + (size_t)(r0 + row) * NN + 8 * g);
  const f32x4* s2p  = (const f32x4*)(s2g + 8 * g);
  const bf16x8* bp  = (const bf16x8*)hbF;

  i32x4 a0c = adjp[4 * w], a1c = adjp[4 * w + 1];
  f32x4 s0c = s2p[4 * w],  s1c = s2p[4 * w + 1];
  bf16x8 b0c = bp[(size_t)(w * 4 + 0) * 64 + l];
  bf16x8 b1c = bp[(size_t)(w * 4 + 1) * 64 + l];
  bf16x8 b2c = bp[(size_t)(w * 4 + 2) * 64 + l];
  bf16x8 b3c = bp[(size_t)(w * 4 + 3) * 64 + l];

  float dsum = 0.f;
  for (int n = w; n < 512; n += 8) {
    const int nn = (n + 8 < 512) ? (n + 8) : w;  // depth-1 prefetch (wrap=dummy)
    i32x4 a0n = adjp[4 * nn], a1n = adjp[4 * nn + 1];
    f32x4 s0n = s2p[4 * nn],  s1n = s2p[4 * nn + 1];
    bf16x8 b0n = bp[(size_t)(nn * 4 + 0) * 64 + l];
    bf16x8 b1n = bp[(size_t)(nn * 4 + 1) * 64 + l];
    bf16x8 b2n = bp[(size_t)(nn * 4 + 2) * 64 + l];
    bf16x8 b3n = bp[(size_t)(nn * 4 + 3) * 64 + l];

    bf16x8 af;
#pragma unroll
    for (int e = 0; e < 8; e++) {
      float x = s1r + ((e < 4) ? s0c[e] : s1c[e - 4]);
      x = fmaxf(x, SLOPE * x);          // leaky-relu (slope<1)
      float p = __expf(x - Mi);         // in (0,1]
      const int ad = (e < 4) ? a0c[e] : a1c[e - 4];
      p = (ad > 0) ? p : 0.f;
      dsum += p;
      af[e] = (short)f2bf(p);
    }
    acc0 = __builtin_amdgcn_mfma_f32_32x32x16_bf16(af, b0c, acc0, 0, 0, 0);
    acc1 = __builtin_amdgcn_mfma_f32_32x32x16_bf16(af, b1c, acc1, 0, 0, 0);
    acc2 = __builtin_amdgcn_mfma_f32_32x32x16_bf16(af, b2c, acc2, 0, 0, 0);
    acc3 = __builtin_amdgcn_mfma_f32_32x32x16_bf16(af, b3c, acc3, 0, 0, 0);

    a0c = a0n; a1c = a1n; s0c = s0n; s1c = s1n;
    b0c = b0n; b1c = b1n; b2c = b2n; b3c = b3n;
  }

  // ---- denominator: combine k-halves, then across 8 waves via LDS ----
  dsum += __shfl_xor(dsum, 32);
  if (l < 32) lred[w * 32 + l] = dsum;
  __syncthreads();
  if (t < 32) {
    float d = 0.f;
#pragma unroll
    for (int w8 = 0; w8 < 8; w8++) d += lred[w8 * 32 + t];
    lred[256 + t] = d;
  }
  __syncthreads();
  const float myden = fmaxf(lred[256 + (t >> 4)], 1e-30f);
  __syncthreads();

  // ---- accumulator reduce across waves (staged: 4 bufs, write then add) ----
  const int colw = l & 31;
  if (w < 4) {
    st16(&lred[w * 4096 + 0 * 32 + colw], acc0, g);
    st16(&lred[w * 4096 + 1 * 32 + colw], acc1, g);
    st16(&lred[w * 4096 + 2 * 32 + colw], acc2, g);
    st16(&lred[w * 4096 + 3 * 32 + colw], acc3, g);
  }
  __syncthreads();
  if (w >= 4) {
    ad16(&lred[(w - 4) * 4096 + 0 * 32 + colw], acc0, g);
    ad16(&lred[(w - 4) * 4096 + 1 * 32 + colw], acc1, g);
    ad16(&lred[(w - 4) * 4096 + 2 * 32 + colw], acc2, g);
    ad16(&lred[(w - 4) * 4096 + 3 * 32 + colw], acc3, g);
  }
  __syncthreads();

  // ---- final: sum 4 buffers, normalize, elu, store ----
  const int orow = t >> 4;
  const int oc = (t & 15) * 8;
  float o[8];
#pragma unroll
  for (int i = 0; i < 8; i++) o[i] = 0.f;
#pragma unroll
  for (int b = 0; b < 4; b++)
#pragma unroll
    for (int i = 0; i < 8; i++) o[i] += lred[b * 4096 + orow * 128 + oc + i];

  float res[8];
#pragma unroll
  for (int i = 0; i < 8; i++) {
    float v = o[i] / myden;
    res[i] = (v > 0.f) ? v : expm1f(v);
  }
  float* op = out + (size_t)(r0 + orow) * OUTF + oc;
  *(f32x4*)op = (f32x4){res[0], res[1], res[2], res[3]};
  *(f32x4*)(op + 4) = (f32x4){res[4], res[5], res[6], res[7]};
}

extern "C" void kernel_launch(void* const* d_in, const int* in_sizes, int n_in,
                              void* d_out, int out_size, void* d_ws, size_t ws_size,
                              hipStream_t stream) {
  (void)in_sizes; (void)n_in; (void)out_size; (void)ws_size;
  const float* X  = (const float*)d_in[0];
  const int*  adj = (const int*)d_in[1];
  const float* W  = (const float*)d_in[2];
  const float* a  = (const float*)d_in[3];
  float* out = (float*)d_out;

  u16*   hbF = (u16*)d_ws;                                   // 2 MB
  float* s1  = (float*)((char*)d_ws + (size_t)2 * 1024 * 1024);
  float* s2  = s1 + NN;
  float* s2m = s2 + NN;

  gat_k1<<<NN / 32, 256, 0, stream>>>(X, W, a, hbF, s1, s2);
  gat_k2<<<1, 256, 0, stream>>>(s2, s2m);
  gat_k3<<<NN / 32, 512, 0, stream>>>(adj, hbF, s1, s2, s2m, out);
}

// Round 2
// 116.560 us; speedup vs baseline: 1.0051x; 1.0051x over previous
//
#include <hip/hip_runtime.h>
#include <hip/hip_bf16.h>

#define NN   8192
#define INF_ 256
#define OUTF 128
#define SLOPE 0.2f

typedef float f32x4  __attribute__((ext_vector_type(4)));
typedef float f32x16 __attribute__((ext_vector_type(16)));
typedef short bf16x8 __attribute__((ext_vector_type(8)));
typedef int   i32x4  __attribute__((ext_vector_type(4)));
typedef unsigned short u16;
typedef u16 u16x4 __attribute__((ext_vector_type(4)));

__device__ __forceinline__ u16 f2bf(float f) {
  return __builtin_bit_cast(u16, __float2bfloat16(f));
}

// ---------------------------------------------------------------------------
// K1: h = X @ W (fp32). Writes:
//  - hbF: bf16 copy of h in MFMA-B-fragment order:
//      elem(j,col) -> ((J*4 + c)*64 + x + 32*g)*8 + e
//      J=j>>4, g=(j>>3)&1, e=j&7, c=col>>5, x=col&31
//  - s1[i] = h[i,:]@a1, s2[i] = h[i,:]@a2  (fp32)
// ---------------------------------------------------------------------------
__global__ __launch_bounds__(256) void gat_k1(
    const float* __restrict__ X, const float* __restrict__ W,
    const float* __restrict__ a, u16* __restrict__ hbF,
    float* __restrict__ s1, float* __restrict__ s2) {
  __shared__ float xs[32 * INF_];
  const int t = threadIdx.x;
  const int r0 = blockIdx.x * 32;
  {
    const f32x4* src = (const f32x4*)(X + (size_t)r0 * INF_);
    f32x4* dst = (f32x4*)xs;
    for (int i = t; i < 32 * INF_ / 4; i += 256) dst[i] = src[i];
  }
  __syncthreads();
  const int cg = t & 31;   // 4-col group
  const int rg = t >> 5;   // 4-row group (0..7)
  float acc[4][4];
#pragma unroll
  for (int i = 0; i < 4; i++)
#pragma unroll
    for (int j = 0; j < 4; j++) acc[i][j] = 0.f;

  for (int k = 0; k < INF_; k += 4) {
    f32x4 xv[4];
#pragma unroll
    for (int i = 0; i < 4; i++) xv[i] = *(const f32x4*)&xs[(rg * 4 + i) * INF_ + k];
#pragma unroll
    for (int kk = 0; kk < 4; kk++) {
      f32x4 wv = *(const f32x4*)&W[(k + kk) * OUTF + cg * 4];
#pragma unroll
      for (int i = 0; i < 4; i++)
#pragma unroll
        for (int j = 0; j < 4; j++) acc[i][j] = fmaf(xv[i][kk], wv[j], acc[i][j]);
    }
  }

  f32x4 a1v = *(const f32x4*)&a[cg * 4];
  f32x4 a2v = *(const f32x4*)&a[OUTF + cg * 4];
  float p1[4], p2[4];
#pragma unroll
  for (int i = 0; i < 4; i++) {
    p1[i] = acc[i][0] * a1v[0] + acc[i][1] * a1v[1] + acc[i][2] * a1v[2] + acc[i][3] * a1v[3];
    p2[i] = acc[i][0] * a2v[0] + acc[i][1] * a2v[1] + acc[i][2] * a2v[2] + acc[i][3] * a2v[3];
  }
#pragma unroll
  for (int m = 1; m < 32; m <<= 1) {
#pragma unroll
    for (int i = 0; i < 4; i++) {
      p1[i] += __shfl_xor(p1[i], m);
      p2[i] += __shfl_xor(p2[i], m);
    }
  }
  if (cg == 0) {
#pragma unroll
    for (int i = 0; i < 4; i++) {
      s1[r0 + rg * 4 + i] = p1[i];
      s2[r0 + rg * 4 + i] = p2[i];
    }
  }

  const int R0 = r0 + rg * 4;
  const int J  = R0 >> 4;
  const int gg = (R0 >> 3) & 1;
  const int e0 = R0 & 7;
#pragma unroll
  for (int j = 0; j < 4; j++) {
    const int C = cg * 4 + j;
    u16x4 pk;
#pragma unroll
    for (int i = 0; i < 4; i++) pk[i] = f2bf(acc[i][j]);
    size_t flat = ((size_t)(J * 4 + (C >> 5)) * 64 + (C & 31) + 32 * gg) * 8 + e0;
    *(u16x4*)(hbF + flat) = pk;
  }
}

// ---------------------------------------------------------------------------
// K2: s2max = max(s2)
// ---------------------------------------------------------------------------
__global__ __launch_bounds__(256) void gat_k2(const float* __restrict__ s2,
                                              float* __restrict__ s2m) {
  __shared__ float sm[4];
  const int t = threadIdx.x;
  float m = -1e30f;
  for (int i = t; i < NN; i += 256) m = fmaxf(m, s2[i]);
#pragma unroll
  for (int k = 1; k < 64; k <<= 1) m = fmaxf(m, __shfl_xor(m, k));
  if ((t & 63) == 0) sm[t >> 6] = m;
  __syncthreads();
  if (t == 0) *s2m = fmaxf(fmaxf(sm[0], sm[1]), fmaxf(sm[2], sm[3]));
}

// ---------------------------------------------------------------------------
// K3: fused mask+lrelu+softmax+PV with LDS-staged adj (double-buffered).
// 256 blocks x 8 waves. Block = 32 rows. Tile = 256 j (32 KB int32).
// Stage: coalesced global->reg->LDS (XOR-swizzled). Compute: LDS fragment
// reads + exp/mask + 32x32x16 bf16 MFMA. Pipeline depth 2 (regs hold t+1,
// loads for t+2 in flight during compute of t).
// ---------------------------------------------------------------------------
__device__ __forceinline__ void st16(float* dst, const f32x16& A, int g) {
#pragma unroll
  for (int r = 0; r < 16; r++) {
    const int dr = (r & 3) + 8 * (r >> 2) + 4 * g;
    dst[dr * 128] = A[r];
  }
}
__device__ __forceinline__ void ad16(float* dst, const f32x16& A, int g) {
#pragma unroll
  for (int r = 0; r < 16; r++) {
    const int dr = (r & 3) + 8 * (r >> 2) + 4 * g;
    dst[dr * 128] += A[r];
  }
}

__global__ __launch_bounds__(512, 2) void gat_k3(
    const int* __restrict__ adj, const u16* __restrict__ hbF,
    const float* __restrict__ s1g, const float* __restrict__ s2g,
    const float* __restrict__ s2maxp, float* __restrict__ out) {
  __shared__ int adjs[2 * 32 * 256];  // 64 KB; aliased as lred in epilogue
  const int t = threadIdx.x;
  const int w = t >> 6;
  const int l = t & 63;
  const int r0 = blockIdx.x * 32;
  const int row = l & 31;
  const int g = l >> 5;

  const float s1r = s1g[r0 + row];
  const float s2m = *s2maxp;
  float Mi = s1r + s2m;
  Mi = fmaxf(Mi, SLOPE * Mi);  // lrelu of upper bound >= all row scores

  f32x16 acc0 = 0.f, acc1 = 0.f, acc2 = 0.f, acc3 = 0.f;

  // ---- staging setup: thread -> (srow = t>>4, 16-int column group) ----
  const int srow = t >> 4;
  const int sc4 = (t & 15) * 4;  // int offset within each 64-int group
  const int* gsrc = adj + (size_t)(r0 + srow) * NN + sc4;
  const int swz_s = (srow & 7) << 2;  // staging-side XOR (int units)
  const int swz_r = (row & 7) << 2;   // read-side XOR (int units)

  i32x4 st[4];
#define STAGE_LOAD(TL)                                         \
  {                                                            \
    const int* p_ = gsrc + 256 * (TL);                         \
    st[0] = *(const i32x4*)(p_);                               \
    st[1] = *(const i32x4*)(p_ + 64);                          \
    st[2] = *(const i32x4*)(p_ + 128);                         \
    st[3] = *(const i32x4*)(p_ + 192);                         \
  }
#define STAGE_WRITE(BUF)                                                    \
  {                                                                         \
    int* b_ = &adjs[(BUF) * 8192 + srow * 256];                             \
    *(i32x4*)(b_ + ((sc4 + 0) ^ swz_s))   = st[0];                          \
    *(i32x4*)(b_ + ((sc4 + 64) ^ swz_s))  = st[1];                          \
    *(i32x4*)(b_ + ((sc4 + 128) ^ swz_s)) = st[2];                          \
    *(i32x4*)(b_ + ((sc4 + 192) ^ swz_s)) = st[3];                          \
  }

  const bf16x8* bp = (const bf16x8*)hbF;
  float dsum = 0.f;

  STAGE_LOAD(0);
  STAGE_WRITE(0);
  STAGE_LOAD(1);
  __syncthreads();

  int cur = 0;
  for (int tt = 0; tt < 32; tt++) {
    // prefetch B fragments for both inner k-steps of this tile
    bf16x8 b[8];
    const int n0 = 16 * tt + w;
#pragma unroll
    for (int k = 0; k < 2; k++) {
      const int n = n0 + 8 * k;
#pragma unroll
      for (int q = 0; q < 4; q++)
        b[k * 4 + q] = bp[(size_t)(n * 4 + q) * 64 + l];
    }

    const int* abuf = &adjs[cur * 8192 + row * 256];
#pragma unroll
    for (int k = 0; k < 2; k++) {
      const int jj0 = 128 * k + 16 * w + 8 * g;
      i32x4 A0 = *(const i32x4*)(abuf + ((jj0) ^ swz_r));
      i32x4 A1 = *(const i32x4*)(abuf + ((jj0 + 4) ^ swz_r));
      const int j0 = 256 * tt + jj0;
      f32x4 s0 = *(const f32x4*)(s2g + j0);
      f32x4 s1v = *(const f32x4*)(s2g + j0 + 4);
      bf16x8 af;
#pragma unroll
      for (int e = 0; e < 8; e++) {
        float x = s1r + ((e < 4) ? s0[e] : s1v[e - 4]);
        x = fmaxf(x, SLOPE * x);          // leaky-relu (slope<1)
        float p = __expf(x - Mi);         // in (0,1]
        const int ad = (e < 4) ? A0[e] : A1[e - 4];
        p = (ad > 0) ? p : 0.f;
        dsum += p;
        af[e] = (short)f2bf(p);
      }
      acc0 = __builtin_amdgcn_mfma_f32_32x32x16_bf16(af, b[k * 4 + 0], acc0, 0, 0, 0);
      acc1 = __builtin_amdgcn_mfma_f32_32x32x16_bf16(af, b[k * 4 + 1], acc1, 0, 0, 0);
      acc2 = __builtin_amdgcn_mfma_f32_32x32x16_bf16(af, b[k * 4 + 2], acc2, 0, 0, 0);
      acc3 = __builtin_amdgcn_mfma_f32_32x32x16_bf16(af, b[k * 4 + 3], acc3, 0, 0, 0);
    }

    // write tile tt+1 (held in regs) to the other buffer; issue loads tt+2
    STAGE_WRITE(cur ^ 1);
    STAGE_LOAD(tt + 2 < 32 ? tt + 2 : 0);
    __syncthreads();
    cur ^= 1;
  }

  float* lred = (float*)adjs;  // safe: final barrier above drained all reads

  // ---- denominator: combine k-halves, then across 8 waves via LDS ----
  dsum += __shfl_xor(dsum, 32);
  if (l < 32) lred[w * 32 + l] = dsum;
  __syncthreads();
  if (t < 32) {
    float d = 0.f;
#pragma unroll
    for (int w8 = 0; w8 < 8; w8++) d += lred[w8 * 32 + t];
    lred[256 + t] = d;
  }
  __syncthreads();
  const float myden = fmaxf(lred[256 + (t >> 4)], 1e-30f);
  __syncthreads();

  // ---- accumulator reduce across waves (staged: 4 bufs, write then add) ----
  const int colw = l & 31;
  if (w < 4) {
    st16(&lred[w * 4096 + 0 * 32 + colw], acc0, g);
    st16(&lred[w * 4096 + 1 * 32 + colw], acc1, g);
    st16(&lred[w * 4096 + 2 * 32 + colw], acc2, g);
    st16(&lred[w * 4096 + 3 * 32 + colw], acc3, g);
  }
  __syncthreads();
  if (w >= 4) {
    ad16(&lred[(w - 4) * 4096 + 0 * 32 + colw], acc0, g);
    ad16(&lred[(w - 4) * 4096 + 1 * 32 + colw], acc1, g);
    ad16(&lred[(w - 4) * 4096 + 2 * 32 + colw], acc2, g);
    ad16(&lred[(w - 4) * 4096 + 3 * 32 + colw], acc3, g);
  }
  __syncthreads();

  // ---- final: sum 4 buffers, normalize, elu, store ----
  const int orow = t >> 4;
  const int oc = (t & 15) * 8;
  float o[8];
#pragma unroll
  for (int i = 0; i < 8; i++) o[i] = 0.f;
#pragma unroll
  for (int bq = 0; bq < 4; bq++)
#pragma unroll
    for (int i = 0; i < 8; i++) o[i] += lred[bq * 4096 + orow * 128 + oc + i];

  float res[8];
#pragma unroll
  for (int i = 0; i < 8; i++) {
    float v = o[i] / myden;
    res[i] = (v > 0.f) ? v : expm1f(v);
  }
  float* op = out + (size_t)(r0 + orow) * OUTF + oc;
  *(f32x4*)op = (f32x4){res[0], res[1], res[2], res[3]};
  *(f32x4*)(op + 4) = (f32x4){res[4], res[5], res[6], res[7]};
}

extern "C" void kernel_launch(void* const* d_in, const int* in_sizes, int n_in,
                              void* d_out, int out_size, void* d_ws, size_t ws_size,
                              hipStream_t stream) {
  (void)in_sizes; (void)n_in; (void)out_size; (void)ws_size;
  const float* X  = (const float*)d_in[0];
  const int*  adj = (const int*)d_in[1];
  const float* W  = (const float*)d_in[2];
  const float* a  = (const float*)d_in[3];
  float* out = (float*)d_out;

  u16*   hbF = (u16*)d_ws;                                   // 2 MB
  float* s1  = (float*)((char*)d_ws + (size_t)2 * 1024 * 1024);
  float* s2  = s1 + NN;
  float* s2m = s2 + NN;

  gat_k1<<<NN / 32, 256, 0, stream>>>(X, W, a, hbF, s1, s2);
  gat_k2<<<1, 256, 0, stream>>>(s2, s2m);
  gat_k3<<<NN / 32, 512, 0, stream>>>(adj, hbF, s1, s2, s2m, out);
}

// Round 3
// 110.086 us; speedup vs baseline: 1.0642x; 1.0588x over previous
//
#include <hip/hip_runtime.h>
#include <hip/hip_bf16.h>

#define NN   8192
#define INF_ 256
#define OUTF 128
#define SLOPE 0.2f
#define NJC  4          // j-chunks (blocks splitting the j dimension)
#define JCHUNK (NN / NJC)   // 2048
#define NT   (JCHUNK / 128) // 16 tiles of 128 j

typedef float f32x4  __attribute__((ext_vector_type(4)));
typedef float f32x16 __attribute__((ext_vector_type(16)));
typedef short bf16x8 __attribute__((ext_vector_type(8)));
typedef int   i32x4  __attribute__((ext_vector_type(4)));
typedef unsigned short u16;
typedef u16 u16x4 __attribute__((ext_vector_type(4)));

__device__ __forceinline__ u16 f2bf(float f) {
  return __builtin_bit_cast(u16, __float2bfloat16(f));
}

// ---------------------------------------------------------------------------
// K1: h = X @ W (fp32). Writes hbF (bf16, MFMA-B-fragment order), s1, s2.
// ---------------------------------------------------------------------------
__global__ __launch_bounds__(256) void gat_k1(
    const float* __restrict__ X, const float* __restrict__ W,
    const float* __restrict__ a, u16* __restrict__ hbF,
    float* __restrict__ s1, float* __restrict__ s2) {
  __shared__ float xs[32 * INF_];
  const int t = threadIdx.x;
  const int r0 = blockIdx.x * 32;
  {
    const f32x4* src = (const f32x4*)(X + (size_t)r0 * INF_);
    f32x4* dst = (f32x4*)xs;
    for (int i = t; i < 32 * INF_ / 4; i += 256) dst[i] = src[i];
  }
  __syncthreads();
  const int cg = t & 31;
  const int rg = t >> 5;
  float acc[4][4];
#pragma unroll
  for (int i = 0; i < 4; i++)
#pragma unroll
    for (int j = 0; j < 4; j++) acc[i][j] = 0.f;

  for (int k = 0; k < INF_; k += 4) {
    f32x4 xv[4];
#pragma unroll
    for (int i = 0; i < 4; i++) xv[i] = *(const f32x4*)&xs[(rg * 4 + i) * INF_ + k];
#pragma unroll
    for (int kk = 0; kk < 4; kk++) {
      f32x4 wv = *(const f32x4*)&W[(k + kk) * OUTF + cg * 4];
#pragma unroll
      for (int i = 0; i < 4; i++)
#pragma unroll
        for (int j = 0; j < 4; j++) acc[i][j] = fmaf(xv[i][kk], wv[j], acc[i][j]);
    }
  }

  f32x4 a1v = *(const f32x4*)&a[cg * 4];
  f32x4 a2v = *(const f32x4*)&a[OUTF + cg * 4];
  float p1[4], p2[4];
#pragma unroll
  for (int i = 0; i < 4; i++) {
    p1[i] = acc[i][0] * a1v[0] + acc[i][1] * a1v[1] + acc[i][2] * a1v[2] + acc[i][3] * a1v[3];
    p2[i] = acc[i][0] * a2v[0] + acc[i][1] * a2v[1] + acc[i][2] * a2v[2] + acc[i][3] * a2v[3];
  }
#pragma unroll
  for (int m = 1; m < 32; m <<= 1) {
#pragma unroll
    for (int i = 0; i < 4; i++) {
      p1[i] += __shfl_xor(p1[i], m);
      p2[i] += __shfl_xor(p2[i], m);
    }
  }
  if (cg == 0) {
#pragma unroll
    for (int i = 0; i < 4; i++) {
      s1[r0 + rg * 4 + i] = p1[i];
      s2[r0 + rg * 4 + i] = p2[i];
    }
  }

  const int R0 = r0 + rg * 4;
  const int J  = R0 >> 4;
  const int gg = (R0 >> 3) & 1;
  const int e0 = R0 & 7;
#pragma unroll
  for (int j = 0; j < 4; j++) {
    const int C = cg * 4 + j;
    u16x4 pk;
#pragma unroll
    for (int i = 0; i < 4; i++) pk[i] = f2bf(acc[i][j]);
    size_t flat = ((size_t)(J * 4 + (C >> 5)) * 64 + (C & 31) + 32 * gg) * 8 + e0;
    *(u16x4*)(hbF + flat) = pk;
  }
}

// ---------------------------------------------------------------------------
// K2: s2max = max(s2)
// ---------------------------------------------------------------------------
__global__ __launch_bounds__(256) void gat_k2(const float* __restrict__ s2,
                                              float* __restrict__ s2m) {
  __shared__ float sm[4];
  const int t = threadIdx.x;
  float m = -1e30f;
  for (int i = t; i < NN; i += 256) m = fmaxf(m, s2[i]);
#pragma unroll
  for (int k = 1; k < 64; k <<= 1) m = fmaxf(m, __shfl_xor(m, k));
  if ((t & 63) == 0) sm[t >> 6] = m;
  __syncthreads();
  if (t == 0) *s2m = fmaxf(fmaxf(sm[0], sm[1]), fmaxf(sm[2], sm[3]));
}

// ---------------------------------------------------------------------------
// K3: fused mask+lrelu+exp+PV over a 32-row x 2048-j slice. Writes fp32
// partial (32x128) and partial denominator (32) to workspace.
// Grid 1024 = 256 row-groups x 4 j-chunks; 512 threads (8 waves).
// LDS: 2 x [32][128] int tiles, full 5-bit XOR swizzle (2-way max = free).
// ---------------------------------------------------------------------------
__device__ __forceinline__ void st16(float* dst, const f32x16& A, int g) {
#pragma unroll
  for (int r = 0; r < 16; r++) {
    const int dr = (r & 3) + 8 * (r >> 2) + 4 * g;
    dst[dr * 128] = A[r];
  }
}
__device__ __forceinline__ void ad16(float* dst, const f32x16& A, int g) {
#pragma unroll
  for (int r = 0; r < 16; r++) {
    const int dr = (r & 3) + 8 * (r >> 2) + 4 * g;
    dst[dr * 128] += A[r];
  }
}

__global__ __launch_bounds__(512, 4) void gat_k3(
    const int* __restrict__ adj, const u16* __restrict__ hbF,
    const float* __restrict__ s1g, const float* __restrict__ s2g,
    const float* __restrict__ s2maxp, float* __restrict__ part,
    float* __restrict__ dpart) {
  __shared__ int adjs[2 * 4096];   // 32 KB, reused as float lred[8192] in epilogue
  __shared__ float dred[256];
  const int t = threadIdx.x;
  const int w = t >> 6;
  const int l = t & 63;
  const int rb = blockIdx.x & 255;
  const int jc = blockIdx.x >> 8;
  const int r0 = rb * 32;
  const int j0 = jc * JCHUNK;
  const int row = l & 31;
  const int g = l >> 5;

  const float s1r = s1g[r0 + row];
  const float s2m = *s2maxp;
  float Mi = s1r + s2m;
  Mi = fmaxf(Mi, SLOPE * Mi);  // lrelu of upper bound >= all row scores

  f32x16 acc0 = 0.f, acc1 = 0.f, acc2 = 0.f, acc3 = 0.f;

  // ---- staging: thread -> (srow = t>>4, two 16B col groups, parity-split) --
  const int srow = t >> 4;
  const int scg = t & 15;
  const int cA = 4 * scg + ((srow & 1) ? 64 : 0);
  const int cB = 4 * scg + ((srow & 1) ? 0 : 64);
  const int slotA = ((cA >> 2) ^ srow) & 31;
  const int slotB = ((cB >> 2) ^ srow) & 31;
  const int* gsrc = adj + (size_t)(r0 + srow) * NN + j0;

  i32x4 stA, stB;
#define STAGE_LOAD(TL)                              \
  {                                                 \
    const int* p_ = gsrc + 128 * (TL);              \
    stA = *(const i32x4*)(p_ + cA);                 \
    stB = *(const i32x4*)(p_ + cB);                 \
  }
#define STAGE_WRITE(BUF)                            \
  {                                                 \
    int* b_ = &adjs[(BUF) * 4096 + srow * 128];     \
    *(i32x4*)(b_ + slotA * 4) = stA;                \
    *(i32x4*)(b_ + slotB * 4) = stB;                \
  }

  // ---- compute-side LDS read slots (full-row XOR: 2-way max) ----
  const int c0 = 16 * w + 8 * g;
  const int sl0 = (((c0 >> 2) + 0) ^ row) & 31;
  const int sl1 = (((c0 >> 2) + 1) ^ row) & 31;

  const bf16x8* bp = (const bf16x8*)hbF;
  const float* s2b = s2g + j0;
  float dsum = 0.f;

  STAGE_LOAD(0);
  STAGE_WRITE(0);
  STAGE_LOAD(1);
  __syncthreads();

  int cur = 0;
  for (int tt = 0; tt < NT; tt++) {
    // B fragments for this tile's k-step (wave w owns k-step w of 8)
    const int n = jc * 128 + 8 * tt + w;
    const bf16x8* bq = bp + (size_t)(n * 4) * 64 + l;
    bf16x8 b0 = bq[0], b1 = bq[64], b2 = bq[128], b3 = bq[192];

    const int* abuf = &adjs[cur * 4096 + row * 128];
    i32x4 A0 = *(const i32x4*)(abuf + sl0 * 4);
    i32x4 A1 = *(const i32x4*)(abuf + sl1 * 4);
    f32x4 s0  = *(const f32x4*)(s2b + 128 * tt + c0);
    f32x4 s1v = *(const f32x4*)(s2b + 128 * tt + c0 + 4);

    bf16x8 af;
#pragma unroll
    for (int e = 0; e < 8; e++) {
      float x = s1r + ((e < 4) ? s0[e] : s1v[e - 4]);
      x = fmaxf(x, SLOPE * x);          // leaky-relu (slope<1)
      float p = __expf(x - Mi);         // in (0,1]
      const int ad = (e < 4) ? A0[e] : A1[e - 4];
      p = (ad > 0) ? p : 0.f;
      dsum += p;
      af[e] = (short)f2bf(p);
    }
    acc0 = __builtin_amdgcn_mfma_f32_32x32x16_bf16(af, b0, acc0, 0, 0, 0);
    acc1 = __builtin_amdgcn_mfma_f32_32x32x16_bf16(af, b1, acc1, 0, 0, 0);
    acc2 = __builtin_amdgcn_mfma_f32_32x32x16_bf16(af, b2, acc2, 0, 0, 0);
    acc3 = __builtin_amdgcn_mfma_f32_32x32x16_bf16(af, b3, acc3, 0, 0, 0);

    if (tt + 1 < NT) STAGE_WRITE(cur ^ 1);
    if (tt + 2 < NT) STAGE_LOAD(tt + 2);
    __syncthreads();
    cur ^= 1;
  }

  // ---- denominator partial ----
  dsum += __shfl_xor(dsum, 32);
  if (l < 32) dred[w * 32 + l] = dsum;

  // ---- accumulator reduce across 8 waves into 2 LDS bufs (4 rounds) ----
  float* lred = (float*)adjs;
  const int colw = l & 31;
  if (w < 2) {
    st16(&lred[w * 4096 + 0 * 32 + colw], acc0, g);
    st16(&lred[w * 4096 + 1 * 32 + colw], acc1, g);
    st16(&lred[w * 4096 + 2 * 32 + colw], acc2, g);
    st16(&lred[w * 4096 + 3 * 32 + colw], acc3, g);
  }
  __syncthreads();
  if (t < 32) {
    float d = 0.f;
#pragma unroll
    for (int w8 = 0; w8 < 8; w8++) d += dred[w8 * 32 + t];
    dpart[jc * NN + r0 + t] = d;
  }
  if (w == 2 || w == 3) {
    ad16(&lred[(w - 2) * 4096 + 0 * 32 + colw], acc0, g);
    ad16(&lred[(w - 2) * 4096 + 1 * 32 + colw], acc1, g);
    ad16(&lred[(w - 2) * 4096 + 2 * 32 + colw], acc2, g);
    ad16(&lred[(w - 2) * 4096 + 3 * 32 + colw], acc3, g);
  }
  __syncthreads();
  if (w == 4 || w == 5) {
    ad16(&lred[(w - 4) * 4096 + 0 * 32 + colw], acc0, g);
    ad16(&lred[(w - 4) * 4096 + 1 * 32 + colw], acc1, g);
    ad16(&lred[(w - 4) * 4096 + 2 * 32 + colw], acc2, g);
    ad16(&lred[(w - 4) * 4096 + 3 * 32 + colw], acc3, g);
  }
  __syncthreads();
  if (w == 6 || w == 7) {
    ad16(&lred[(w - 6) * 4096 + 0 * 32 + colw], acc0, g);
    ad16(&lred[(w - 6) * 4096 + 1 * 32 + colw], acc1, g);
    ad16(&lred[(w - 6) * 4096 + 2 * 32 + colw], acc2, g);
    ad16(&lred[(w - 6) * 4096 + 3 * 32 + colw], acc3, g);
  }
  __syncthreads();

  // ---- write fp32 partial: sum the 2 bufs ----
  const int flat = t * 8;  // row = t>>4, col = (t&15)*8
  f32x4 pa = *(f32x4*)&lred[flat];
  f32x4 pb = *(f32x4*)&lred[flat + 4];
  pa += *(f32x4*)&lred[4096 + flat];
  pb += *(f32x4*)&lred[4096 + flat + 4];
  float* pp = part + (size_t)jc * (NN * OUTF) + (size_t)r0 * OUTF + flat;
  *(f32x4*)pp = pa;
  *(f32x4*)(pp + 4) = pb;
}

// ---------------------------------------------------------------------------
// K4: combine 4 partials, divide by denom, elu, store.
// ---------------------------------------------------------------------------
__global__ __launch_bounds__(256) void gat_k4(
    const float* __restrict__ part, const float* __restrict__ dpart,
    float* __restrict__ out) {
  const int idx = blockIdx.x * 256 + threadIdx.x;
  const int e4 = idx * 4;
  const int i = e4 >> 7;
  f32x4 p = {0.f, 0.f, 0.f, 0.f};
  float d = 0.f;
#pragma unroll
  for (int jc = 0; jc < NJC; jc++) {
    p += *(const f32x4*)&part[(size_t)jc * (NN * OUTF) + e4];
    d += dpart[jc * NN + i];
  }
  d = fmaxf(d, 1e-30f);
  f32x4 r;
#pragma unroll
  for (int k = 0; k < 4; k++) {
    float v = p[k] / d;
    r[k] = (v > 0.f) ? v : expm1f(v);
  }
  *(f32x4*)&out[e4] = r;
}

extern "C" void kernel_launch(void* const* d_in, const int* in_sizes, int n_in,
                              void* d_out, int out_size, void* d_ws, size_t ws_size,
                              hipStream_t stream) {
  (void)in_sizes; (void)n_in; (void)out_size; (void)ws_size;
  const float* X  = (const float*)d_in[0];
  const int*  adj = (const int*)d_in[1];
  const float* W  = (const float*)d_in[2];
  const float* a  = (const float*)d_in[3];
  float* out = (float*)d_out;

  char* ws = (char*)d_ws;
  u16*   hbF   = (u16*)ws;                                  // 2 MB
  float* s1    = (float*)(ws + (2u << 20));                 // 32 KB
  float* s2    = (float*)(ws + (2u << 20) + (32u << 10));   // 32 KB
  float* s2m   = (float*)(ws + (2u << 20) + (64u << 10));   // 4 B
  float* dpart = (float*)(ws + (2u << 20) + (128u << 10));  // 128 KB
  float* part  = (float*)(ws + (4u << 20));                 // 16 MB

  gat_k1<<<NN / 32, 256, 0, stream>>>(X, W, a, hbF, s1, s2);
  gat_k2<<<1, 256, 0, stream>>>(s2, s2m);
  gat_k3<<<256 * NJC, 512, 0, stream>>>(adj, hbF, s1, s2, s2m, part, dpart);
  gat_k4<<<(NN * OUTF / 4) / 256, 256, 0, stream>>>(part, dpart, out);
}